// Round 11
// baseline (639.227 us; speedup 1.0000x reference)
//
#include <hip/hip_runtime.h>
#include <hip/hip_bf16.h>

// Problem constants (fixed by setup_inputs)
#define B_   4
#define N_   4096
#define KNN_ 32
#define KK_  64          // 2*k
#define MTOT 1048576     // B*N*KK
#define BN_EPS 1e-3f

typedef unsigned int u32;
typedef unsigned long long u64;
typedef __attribute__((ext_vector_type(8))) short bf16x8;
typedef __attribute__((ext_vector_type(4))) float f32x4;

__device__ __forceinline__ ushort f2bf_bits(float f) {   // RNE, finite inputs only
    u32 b = __float_as_uint(f);
    b += 0x7fffu + ((b >> 16) & 1u);
    return (ushort)(b >> 16);
}

// ---------------------------------------------------------------------------
// K1: dual KNN, atomic-free. Round-11: keys[] NOT kept in registers (frees
// 64 AGPRs -> occupancy LDS-capped at 3 waves/SIMD). Keys recomputed with a
// bit-identical fmaf chain in phase C-slow (13% of rows) and phase D.
// grid: 768 blocks = 8 (pr,b) * 96 chunks; 4 waves stride.
// ---------------------------------------------------------------------------
__global__ __launch_bounds__(256, 3) void knn_kernel(
    const float* __restrict__ p1, const float* __restrict__ p2,
    float* __restrict__ feats)
{
    __shared__ float2 cxy[N_];                   // 32 KB
    __shared__ float  cz[N_];                    // 16 KB

    const int tid  = threadIdx.x;
    const int wave = tid >> 6, lane = tid & 63;
    const int pb    = blockIdx.x / 96;           // 0..7
    const int chunk = blockIdx.x % 96;
    const int pr = pb >> 2, b = pb & 3;
    const int start = (chunk * 4096) / 96;
    const int end   = ((chunk + 1) * 4096) / 96;

    const float* srcb = (pr ? p2 : p1) + (size_t)b * 3 * N_;
    for (int n = tid; n < N_; n += 256) {
        float x = srcb[n], y = srcb[N_ + n], z = srcb[2*N_ + n];
        cxy[n] = make_float2(x, y);
        cz[n]  = z;
    }
    __syncthreads();

    const float* p1b = p1 + (size_t)b * 3 * N_;
    const u64 below = (1ull << lane) - 1ull;

    for (int n = start + wave; n < end; n += 4) {
        float qx, qy, qz;
        if (pr == 0) { float2 q = cxy[n]; qx = q.x; qy = q.y; qz = cz[n]; }
        else         { qx = p1b[n]; qy = p1b[N_ + n]; qz = p1b[2*N_ + n]; }
        const float s1 = fmaf(qx, qx, fmaf(qy, qy, qz*qz));

        // bit-identical key of candidate column j (same chain everywhere)
        auto keyAt = [&](int j) -> u32 {
            float2 c = cxy[j * 64 + lane];
            float  z = cz[j * 64 + lane];
            float cw  = fmaf(c.x, c.x, fmaf(c.y, c.y, z*z));
            float dot = fmaf(qx, c.x, fmaf(qy, c.y, qz * z));
            float d2  = fmaf(-2.0f, dot, s1 + cw);
            u32 u = __float_as_uint(d2);
            return u ^ (u32)(((int)u >> 31) | 0x80000000);
        };

        // ---- phase A: two independent kept-4 chains (no key storage) ----
        u32 a0 = 0xFFFFFFFFu, a1 = 0xFFFFFFFFu, a2 = 0xFFFFFFFFu, a3 = 0xFFFFFFFFu;
        u32 b0 = 0xFFFFFFFFu, b1 = 0xFFFFFFFFu, b2 = 0xFFFFFFFFu, b3 = 0xFFFFFFFFu;
        #pragma unroll
        for (int j = 0; j < 32; ++j) {
            {
                u32 key = keyAt(j);
                a3 = min(a3, key);
                u32 t;
                t = min(a2, a3); a3 = max(a2, a3); a2 = t;
                t = min(a1, a2); a2 = max(a1, a2); a1 = t;
                t = min(a0, a1); a1 = max(a0, a1); a0 = t;
            }
            {
                u32 key = keyAt(j + 32);
                b3 = min(b3, key);
                u32 t;
                t = min(b2, b3); b3 = max(b2, b3); b2 = t;
                t = min(b1, b2); b2 = max(b1, b2); b1 = t;
                t = min(b0, b1); b1 = max(b0, b1); b0 = t;
            }
        }
        u32 k0 = a0, k1 = a1, k2 = a2, k3 = a3;
        #pragma unroll
        for (int m = 0; m < 4; ++m) {
            u32 x = (m == 0) ? b0 : (m == 1) ? b1 : (m == 2) ? b2 : b3;
            k3 = min(k3, x);
            u32 t;
            t = min(k2, k3); k3 = max(k2, k3); k2 = t;
            t = min(k1, k2); k2 = max(k1, k2); k1 = t;
            t = min(k0, k1); k1 = max(k0, k1); k0 = t;
        }

        // ---- phase B: bisect rank-31 threshold over kept-4 union ----
        u32 mn = k0, mx = k3;
        #pragma unroll
        for (int off = 1; off < 64; off <<= 1) {
            mn = min(mn, (u32)__shfl_xor((int)mn, off, 64));
            mx = max(mx, (u32)__shfl_xor((int)mx, off, 64));
        }
        u32 lo = mn, hi = mx;
        while (lo < hi) {
            u32 mid = lo + ((hi - lo) >> 1);
            int c = __popcll(__ballot(k0 <= mid)) + __popcll(__ballot(k1 <= mid))
                  + __popcll(__ballot(k2 <= mid)) + __popcll(__ballot(k3 <= mid));
            if (c >= 32) hi = mid; else lo = mid + 1;
        }
        u32 T = lo;

        // ---- phase C: certify (fast path when kept-4 provably complete) ----
        int nl;
        if (__ballot(k3 <= T) == 0ull) {
            nl = __popcll(__ballot(k0 < T)) + __popcll(__ballot(k1 < T))
               + __popcll(__ballot(k2 < T)) + __popcll(__ballot(k3 < T));
        } else {
            nl = 0;
            for (int j = 0; j < 64; ++j) nl += __popcll(__ballot(keyAt(j) < T));
            if (nl > 31) {                  // kept-4 truncated (rare ~0.8%)
                lo = 0u; hi = T;
                while (lo < hi) {
                    u32 mid = lo + ((hi - lo) >> 1);
                    int c = 0;
                    for (int j = 0; j < 64; ++j) c += __popcll(__ballot(keyAt(j) <= mid));
                    if (c >= 32) hi = mid; else lo = mid + 1;
                }
                T = lo;
                nl = 0;
                for (int j = 0; j < 64; ++j) nl += __popcll(__ballot(keyAt(j) < T));
            }
        }
        const int need_eq = 32 - nl;        // >= 1; ties resolved by candidate index

        // ---- phase D: emission; key recomputed, coords reused for emit ----
        float* fout = feats + ((size_t)(b * N_ + n) * KK_ + pr * KNN_) * 4;
        int base = 0, eq_seen = 0;
        #pragma unroll
        for (int j = 0; j < 64; ++j) {
            float2 cx2 = cxy[j * 64 + lane];
            float  cz1 = cz[j * 64 + lane];
            float cw  = fmaf(cx2.x, cx2.x, fmaf(cx2.y, cx2.y, cz1*cz1));
            float dot = fmaf(qx, cx2.x, fmaf(qy, cx2.y, qz * cz1));
            float d2  = fmaf(-2.0f, dot, s1 + cw);
            u32 u = __float_as_uint(d2);
            u32 key = u ^ (u32)(((int)u >> 31) | 0x80000000);
            bool lt = key < T;
            bool eq = key == T;
            u64 mlt = __ballot(lt);
            u64 meq = __ballot(eq);
            if (mlt | meq) {
                int slot = -1;
                if (lt) slot = base + __popcll(mlt & below);
                else if (eq) {
                    int es = eq_seen + __popcll(meq & below);
                    if (es < need_eq) slot = nl + es;
                }
                if (slot >= 0) {
                    float rx = cx2.x - qx, ry = cx2.y - qy, rz = cz1 - qz;
                    float dist = sqrtf(fmaf(rx, rx, fmaf(ry, ry, rz*rz)));
                    *(float4*)(fout + slot * 4) = make_float4(rx, ry, rz, dist);
                }
                base    += __popcll(mlt);
                eq_seen += __popcll(meq);
            }
        }
    }
}

// ---------------------------------------------------------------------------
// K2: 14 global moments of feats (padded counters, one cacheline each).
// ---------------------------------------------------------------------------
__global__ __launch_bounds__(256) void moments_kernel(
    const float4* __restrict__ feats4, float* __restrict__ mom)
{
    __shared__ float part[4][14];
    const int tid = threadIdx.x, lane = tid & 63, wv = tid >> 6;
    float a[14];
    #pragma unroll
    for (int s = 0; s < 14; ++s) a[s] = 0.f;
    for (int idx = blockIdx.x * 256 + tid; idx < MTOT; idx += 256 * 256) {
        float4 f = feats4[idx];
        a[0] += f.x; a[1] += f.y; a[2] += f.z; a[3] += f.w;
        a[4]  = fmaf(f.x, f.x, a[4]);  a[5]  = fmaf(f.x, f.y, a[5]);
        a[6]  = fmaf(f.x, f.z, a[6]);  a[7]  = fmaf(f.x, f.w, a[7]);
        a[8]  = fmaf(f.y, f.y, a[8]);  a[9]  = fmaf(f.y, f.z, a[9]);
        a[10] = fmaf(f.y, f.w, a[10]); a[11] = fmaf(f.z, f.z, a[11]);
        a[12] = fmaf(f.z, f.w, a[12]); a[13] = fmaf(f.w, f.w, a[13]);
    }
    #pragma unroll
    for (int s = 0; s < 14; ++s) {
        #pragma unroll
        for (int off = 1; off < 64; off <<= 1) a[s] += __shfl_xor(a[s], off, 64);
    }
    if (lane == 0) {
        #pragma unroll
        for (int s = 0; s < 14; ++s) part[wv][s] = a[s];
    }
    __syncthreads();
    if (tid < 14) {
        float v = part[0][tid] + part[1][tid] + part[2][tid] + part[3][tid];
        atomicAdd(&mom[tid * 16], v);
    }
}

// ---------------------------------------------------------------------------
// K3: MFMA conv2 (r9 structure): bn1 from moments, y2 -> bf16 y2F + stats2.
// ---------------------------------------------------------------------------
__global__ __launch_bounds__(256) void conv2_mfma(
    const float* __restrict__ feats,
    const float* __restrict__ W1,
    const float* __restrict__ g1, const float* __restrict__ be1,
    const float* __restrict__ W2,
    const float* __restrict__ mom,
    ushort* __restrict__ y2F, float* __restrict__ s2S, float* __restrict__ s2Q)
{
    __shared__ float statS[64], statQ[64];
    const int tid = threadIdx.x;
    const int wid = tid >> 6, l = tid & 63, q = l >> 4, i = l & 15;
    if (tid < 64) { statS[tid] = 0.f; statQ[tid] = 0.f; }

    const float invM = 1.0f / MTOT;
    const float M0 = mom[0*16], M1 = mom[1*16], M2 = mom[2*16], M3 = mom[3*16];
    const float Sxx = mom[4*16],  Sxy = mom[5*16],  Sxz = mom[6*16],  Sxd = mom[7*16];
    const float Syy = mom[8*16],  Syz = mom[9*16],  Syd = mom[10*16];
    const float Szz = mom[11*16], Szd = mom[12*16], Sdd = mom[13*16];

    float4 w1f[16];
    float  c1v[16];
    #pragma unroll
    for (int h = 0; h < 2; ++h)
      #pragma unroll
      for (int j = 0; j < 8; ++j) {
        int ci = h*32 + q*8 + j;
        float w0 = W1[ci*4+0], w1 = W1[ci*4+1], w2 = W1[ci*4+2], w3 = W1[ci*4+3];
        float meanf = (w0*M0 + w1*M1 + w2*M2 + w3*M3) * invM;
        float qq = w0*(w0*Sxx + 2.f*(w1*Sxy + w2*Sxz + w3*Sxd))
                 + w1*(w1*Syy + 2.f*(w2*Syz + w3*Syd))
                 + w2*(w2*Szz + 2.f*w3*Szd)
                 + w3*w3*Sdd;
        float var = qq * invM - meanf * meanf;
        float sc  = g1[ci] * rsqrtf(var + BN_EPS);
        w1f[h*8+j] = make_float4(sc*w0, sc*w1, sc*w2, sc*w3);
        c1v[h*8+j] = fmaf(-sc, meanf, be1[ci]);
      }
    bf16x8 a2[4][2];
    #pragma unroll
    for (int t = 0; t < 4; ++t)
      #pragma unroll
      for (int h = 0; h < 2; ++h)
        #pragma unroll
        for (int j = 0; j < 8; ++j)
          a2[t][h][j] = (short)f2bf_bits(W2[(t*16 + i)*64 + h*32 + q*8 + j]);

    float ssum[16], ssq[16];
    #pragma unroll
    for (int s = 0; s < 16; ++s) { ssum[s] = 0.f; ssq[s] = 0.f; }
    __syncthreads();

    for (int r16 = 0; r16 < 16; ++r16) {
        const int row = blockIdx.x * 16 + r16;
        float4 f = ((const float4*)feats)[row*64 + wid*16 + i];
        bf16x8 xb[2];
        #pragma unroll
        for (int h = 0; h < 2; ++h)
          #pragma unroll
          for (int j = 0; j < 8; ++j) {
            float4 w = w1f[h*8+j];
            float x = fmaxf(fmaf(w.x, f.x, fmaf(w.y, f.y, fmaf(w.z, f.z, fmaf(w.w, f.w, c1v[h*8+j])))), 0.f);
            xb[h][j] = (short)f2bf_bits(x);
          }
        f32x4 acc[4];
        #pragma unroll
        for (int t = 0; t < 4; ++t) acc[t] = (f32x4){0.f,0.f,0.f,0.f};
        #pragma unroll
        for (int t = 0; t < 4; ++t) {
            acc[t] = __builtin_amdgcn_mfma_f32_16x16x32_bf16(a2[t][0], xb[0], acc[t], 0, 0, 0);
            acc[t] = __builtin_amdgcn_mfma_f32_16x16x32_bf16(a2[t][1], xb[1], acc[t], 0, 0, 0);
        }
        ushort* wp = y2F + row*4096 + wid*1024 + q*64 + i*4;
        #pragma unroll
        for (int t = 0; t < 4; ++t) {
            #pragma unroll
            for (int reg = 0; reg < 4; ++reg) {
                float y = acc[t][reg];
                ssum[t*4+reg] += y;
                ssq[t*4+reg]  = fmaf(y, y, ssq[t*4+reg]);
            }
            uint2 pk;
            pk.x = (u32)f2bf_bits(acc[t][0]) | ((u32)f2bf_bits(acc[t][1]) << 16);
            pk.y = (u32)f2bf_bits(acc[t][2]) | ((u32)f2bf_bits(acc[t][3]) << 16);
            *(uint2*)(wp + t*256) = pk;
        }
    }
    #pragma unroll
    for (int s = 0; s < 16; ++s) {
        #pragma unroll
        for (int off = 1; off < 16; off <<= 1) {
            ssum[s] += __shfl_xor(ssum[s], off, 64);
            ssq[s]  += __shfl_xor(ssq[s],  off, 64);
        }
    }
    if (i == 0) {
        #pragma unroll
        for (int s = 0; s < 16; ++s) {
            int co = (s >> 2)*16 + q*4 + (s & 3);
            atomicAdd(&statS[co], ssum[s]);
            atomicAdd(&statQ[co], ssq[s]);
        }
    }
    __syncthreads();
    if (tid < 64) { atomicAdd(&s2S[tid], statS[tid]); atomicAdd(&s2Q[tid], statQ[tid]); }
}

// ---------------------------------------------------------------------------
// K4/K5: MFMA conv3 (r9 structure). FINAL reconstructs coords as q + resi.
// ---------------------------------------------------------------------------
template<bool FINAL>
__global__ __launch_bounds__(256) void conv3_mfma(
    const ushort* __restrict__ y2F,
    const float* __restrict__ g2, const float* __restrict__ be2,
    const float* __restrict__ W3,
    const float* __restrict__ g3, const float* __restrict__ be3,
    const float* __restrict__ s2S, const float* __restrict__ s2Q,
    float* __restrict__ s3S, float* __restrict__ s3Q,
    const float4* __restrict__ feats4, const float* __restrict__ p1,
    float* __restrict__ outp)
{
    __shared__ float statS[128], statQ[128];
    __shared__ float sc3L[128], sh3L[128];
    __shared__ float scoreL[2][64];

    const int tid = threadIdx.x;
    const int wid = tid >> 6, l = tid & 63, q = l >> 4, i = l & 15;

    if (!FINAL) {
        if (tid < 128) { statS[tid] = 0.f; statQ[tid] = 0.f; }
    } else if (tid < 128) {
        float m  = s3S[tid] * (1.0f / MTOT);
        float v  = s3Q[tid] * (1.0f / MTOT) - m * m;
        float sc = g3[tid] * rsqrtf(v + BN_EPS);
        sc3L[tid] = sc;
        sh3L[tid] = fmaf(-sc, m, be3[tid]);
    }

    float sc2v[16], sh2v[16];
    #pragma unroll
    for (int h = 0; h < 2; ++h)
      #pragma unroll
      for (int j = 0; j < 8; ++j) {
        int ci = h*32 + q*8 + j;
        float m  = s2S[ci] * (1.0f / MTOT);
        float v  = s2Q[ci] * (1.0f / MTOT) - m * m;
        float sc = g2[ci] * rsqrtf(v + BN_EPS);
        sc2v[h*8+j] = sc;
        sh2v[h*8+j] = fmaf(-sc, m, be2[ci]);
      }
    bf16x8 a3[8][2];
    #pragma unroll
    for (int t = 0; t < 8; ++t)
      #pragma unroll
      for (int h = 0; h < 2; ++h)
        #pragma unroll
        for (int j = 0; j < 8; ++j)
          a3[t][h][j] = (short)f2bf_bits(W3[(t*16 + i)*64 + h*32 + q*8 + j]);

    float ssum[32], ssq[32];
    if (!FINAL) {
        #pragma unroll
        for (int s = 0; s < 32; ++s) { ssum[s] = 0.f; ssq[s] = 0.f; }
    }
    __syncthreads();

    for (int r16 = 0; r16 < 16; ++r16) {
        const int row = blockIdx.x * 16 + r16;
        const ushort* rp = y2F + row*4096 + wid*1024 + q*128 + i*4;
        uint2 u00 = *(const uint2*)(rp);
        uint2 u01 = *(const uint2*)(rp + 64);
        uint2 u10 = *(const uint2*)(rp + 512);
        uint2 u11 = *(const uint2*)(rp + 576);

        bf16x8 xb[2];
        #pragma unroll
        for (int h = 0; h < 2; ++h) {
            u32 w0 = (h == 0) ? u00.x : u10.x;
            u32 w1 = (h == 0) ? u00.y : u10.y;
            u32 w2 = (h == 0) ? u01.x : u11.x;
            u32 w3 = (h == 0) ? u01.y : u11.y;
            float xf[8];
            xf[0] = __uint_as_float(w0 << 16); xf[1] = __uint_as_float(w0 & 0xffff0000u);
            xf[2] = __uint_as_float(w1 << 16); xf[3] = __uint_as_float(w1 & 0xffff0000u);
            xf[4] = __uint_as_float(w2 << 16); xf[5] = __uint_as_float(w2 & 0xffff0000u);
            xf[6] = __uint_as_float(w3 << 16); xf[7] = __uint_as_float(w3 & 0xffff0000u);
            #pragma unroll
            for (int j = 0; j < 8; ++j) {
                float x = fmaxf(fmaf(sc2v[h*8+j], xf[j], sh2v[h*8+j]), 0.f);
                xb[h][j] = (short)f2bf_bits(x);
            }
        }
        f32x4 acc[8];
        #pragma unroll
        for (int t = 0; t < 8; ++t) acc[t] = (f32x4){0.f,0.f,0.f,0.f};
        #pragma unroll
        for (int t = 0; t < 8; ++t) {
            acc[t] = __builtin_amdgcn_mfma_f32_16x16x32_bf16(a3[t][0], xb[0], acc[t], 0, 0, 0);
            acc[t] = __builtin_amdgcn_mfma_f32_16x16x32_bf16(a3[t][1], xb[1], acc[t], 0, 0, 0);
        }

        if (!FINAL) {
            #pragma unroll
            for (int t = 0; t < 8; ++t)
              #pragma unroll
              for (int reg = 0; reg < 4; ++reg) {
                float y = acc[t][reg];
                ssum[t*4+reg] += y;
                ssq[t*4+reg]  = fmaf(y, y, ssq[t*4+reg]);
              }
        } else {
            float mx = -3.4e38f;
            #pragma unroll
            for (int t = 0; t < 8; ++t) {
                float4 s4 = *(const float4*)&sc3L[t*16 + q*4];
                float4 h4 = *(const float4*)&sh3L[t*16 + q*4];
                mx = fmaxf(mx, fmaf(s4.x, acc[t][0], h4.x));
                mx = fmaxf(mx, fmaf(s4.y, acc[t][1], h4.y));
                mx = fmaxf(mx, fmaf(s4.z, acc[t][2], h4.z));
                mx = fmaxf(mx, fmaf(s4.w, acc[t][3], h4.w));
            }
            mx = fmaxf(mx, __shfl_xor(mx, 16, 64));
            mx = fmaxf(mx, __shfl_xor(mx, 32, 64));
            mx = fmaxf(mx, 0.f);
            if (q == 0) scoreL[r16 & 1][wid*16 + i] = mx;
            __syncthreads();
            if (wid == 0) {
                float sc = scoreL[r16 & 1][l];
                float m2 = sc;
                #pragma unroll
                for (int off = 1; off < 64; off <<= 1) m2 = fmaxf(m2, __shfl_xor(m2, off, 64));
                float e = __expf(sc - m2);
                float se = e;
                #pragma unroll
                for (int off = 1; off < 64; off <<= 1) se += __shfl_xor(se, off, 64);
                float w = e / se;
                const int bb = row >> 12, n = row & 4095;
                float qx = p1[(size_t)bb*3*N_ + n];
                float qy = p1[(size_t)bb*3*N_ + N_ + n];
                float qz = p1[(size_t)bb*3*N_ + 2*N_ + n];
                float4 f4 = feats4[row*64 + l];
                float ox = w * (f4.x + qx), oy = w * (f4.y + qy), oz = w * (f4.z + qz);
                #pragma unroll
                for (int off = 1; off < 64; off <<= 1) {
                    ox += __shfl_xor(ox, off, 64);
                    oy += __shfl_xor(oy, off, 64);
                    oz += __shfl_xor(oz, off, 64);
                }
                if (l == 0) {
                    outp[bb*3*N_ + 0*N_ + n] = ox;
                    outp[bb*3*N_ + 1*N_ + n] = oy;
                    outp[bb*3*N_ + 2*N_ + n] = oz;
                }
            }
        }
    }

    if (!FINAL) {
        #pragma unroll
        for (int s = 0; s < 32; ++s) {
            #pragma unroll
            for (int off = 1; off < 16; off <<= 1) {
                ssum[s] += __shfl_xor(ssum[s], off, 64);
                ssq[s]  += __shfl_xor(ssq[s],  off, 64);
            }
        }
        if (i == 0) {
            #pragma unroll
            for (int s = 0; s < 32; ++s) {
                int co = (s >> 2)*16 + q*4 + (s & 3);
                atomicAdd(&statS[co], ssum[s]);
                atomicAdd(&statQ[co], ssq[s]);
            }
        }
        __syncthreads();
        if (tid < 128) { atomicAdd(&s3S[tid], statS[tid]); atomicAdd(&s3Q[tid], statQ[tid]); }
    }
}

// ---------------------------------------------------------------------------
extern "C" void kernel_launch(void* const* d_in, const int* in_sizes, int n_in,
                              void* d_out, int out_size, void* d_ws, size_t ws_size,
                              hipStream_t stream)
{
    const float* p1  = (const float*)d_in[0];
    const float* p2  = (const float*)d_in[1];
    // d_in[2] = k (always 32), d_in[3] = t (unused by reference)
    const float* W1  = (const float*)d_in[4];
    const float* g1  = (const float*)d_in[6];
    const float* be1 = (const float*)d_in[7];
    const float* W2  = (const float*)d_in[8];
    const float* g2  = (const float*)d_in[10];
    const float* be2 = (const float*)d_in[11];
    const float* W3  = (const float*)d_in[12];
    const float* g3  = (const float*)d_in[14];
    const float* be3 = (const float*)d_in[15];
    // b1 cancels through bn1 (moment fold); b2/b3 cancel through bn2/bn3.

    char* ws = (char*)d_ws;
    const size_t OFF_FEATS = 4096;
    const size_t OFF_Y2    = OFF_FEATS + (size_t)MTOT * 4 * 4;          // 16 MB feats
    const size_t NEEDED    = OFF_Y2 + (size_t)MTOT * 64 * 2;            // 128 MB y2 bf16
    if (ws_size < NEEDED) return;  // fail visibly (wrong output) rather than fault

    float* s2S = (float*)(ws + 512);  float* s2Q = (float*)(ws + 768);
    float* s3S = (float*)(ws + 1024); float* s3Q = (float*)(ws + 1536);
    float* mom = (float*)(ws + 2048);            // 14 counters, 64-B stride each
    float* feats = (float*)(ws + OFF_FEATS);
    ushort* y2F  = (ushort*)(ws + OFF_Y2);

    hipMemsetAsync(ws, 0, 4096, stream);  // zero stats + padded moment counters

    knn_kernel<<<768, 256, 0, stream>>>(p1, p2, feats);
    moments_kernel<<<256, 256, 0, stream>>>((const float4*)feats, mom);
    conv2_mfma<<<1024, 256, 0, stream>>>(feats, W1, g1, be1, W2, mom,
                                         y2F, s2S, s2Q);
    conv3_mfma<false><<<1024, 256, 0, stream>>>(y2F, g2, be2, W3, g3, be3,
                                                s2S, s2Q, s3S, s3Q,
                                                nullptr, nullptr, nullptr);
    conv3_mfma<true><<<1024, 256, 0, stream>>>(y2F, g2, be2, W3, g3, be3,
                                               s2S, s2Q, s3S, s3Q,
                                               (const float4*)feats, p1,
                                               (float*)d_out);
}

// Round 12
// 511.800 us; speedup vs baseline: 1.2490x; 1.2490x over previous
//
#include <hip/hip_runtime.h>
#include <hip/hip_bf16.h>

// Problem constants (fixed by setup_inputs)
#define B_   4
#define N_   4096
#define KNN_ 32
#define KK_  64          // 2*k
#define MTOT 1048576     // B*N*KK
#define BN_EPS 1e-3f

typedef unsigned int u32;
typedef unsigned long long u64;
typedef __attribute__((ext_vector_type(8))) short bf16x8;
typedef __attribute__((ext_vector_type(4))) float f32x4;

__device__ __forceinline__ ushort f2bf_bits(float f) {   // RNE, finite inputs only
    u32 b = __float_as_uint(f);
    b += 0x7fffu + ((b >> 16) & 1u);
    return (ushort)(b >> 16);
}

// ---------------------------------------------------------------------------
// K1: dual KNN, atomic-free (r9 structure: keys in registers, split kept-4
// chains) + fused feats-moment accumulation (14 sums, padded atomics).
// grid: 768 blocks = 8 (pr,b) * 96 chunks; 4 waves stride.
// ---------------------------------------------------------------------------
__global__ __launch_bounds__(256, 3) void knn_kernel(
    const float* __restrict__ p1, const float* __restrict__ p2,
    float* __restrict__ feats, float* __restrict__ mom)
{
    __shared__ float2 cxy[N_];                   // 32 KB
    __shared__ float  cz[N_];                    // 16 KB
    __shared__ float  part[4][14];

    const int tid  = threadIdx.x;
    const int wave = tid >> 6, lane = tid & 63;
    const int pb    = blockIdx.x / 96;           // 0..7
    const int chunk = blockIdx.x % 96;
    const int pr = pb >> 2, b = pb & 3;
    const int start = (chunk * 4096) / 96;
    const int end   = ((chunk + 1) * 4096) / 96;

    const float* srcb = (pr ? p2 : p1) + (size_t)b * 3 * N_;
    for (int n = tid; n < N_; n += 256) {
        float x = srcb[n], y = srcb[N_ + n], z = srcb[2*N_ + n];
        cxy[n] = make_float2(x, y);
        cz[n]  = z;
    }
    __syncthreads();

    const float* p1b = p1 + (size_t)b * 3 * N_;
    const u64 below = (1ull << lane) - 1ull;

    float mm[14];
    #pragma unroll
    for (int s = 0; s < 14; ++s) mm[s] = 0.f;

    for (int n = start + wave; n < end; n += 4) {
        float qx, qy, qz;
        if (pr == 0) { float2 q = cxy[n]; qx = q.x; qy = q.y; qz = cz[n]; }
        else         { qx = p1b[n]; qy = p1b[N_ + n]; qz = p1b[2*N_ + n]; }
        const float s1 = fmaf(qx, qx, fmaf(qy, qy, qz*qz));

        // ---- phase A: keys (once, registers) + two independent kept-4 ----
        u32 keys[64];
        u32 a0 = 0xFFFFFFFFu, a1 = 0xFFFFFFFFu, a2 = 0xFFFFFFFFu, a3 = 0xFFFFFFFFu;
        u32 b0 = 0xFFFFFFFFu, b1 = 0xFFFFFFFFu, b2 = 0xFFFFFFFFu, b3 = 0xFFFFFFFFu;
        #pragma unroll
        for (int j = 0; j < 32; ++j) {
            {
                float2 cA = cxy[j * 64 + lane];
                float  zA = cz[j * 64 + lane];
                float cw  = fmaf(cA.x, cA.x, fmaf(cA.y, cA.y, zA*zA));
                float dot = fmaf(qx, cA.x, fmaf(qy, cA.y, qz * zA));
                float d2  = fmaf(-2.0f, dot, s1 + cw);
                u32 u = __float_as_uint(d2);
                u32 key = u ^ (u32)(((int)u >> 31) | 0x80000000);
                keys[j] = key;
                a3 = min(a3, key);
                u32 t;
                t = min(a2, a3); a3 = max(a2, a3); a2 = t;
                t = min(a1, a2); a2 = max(a1, a2); a1 = t;
                t = min(a0, a1); a1 = max(a0, a1); a0 = t;
            }
            {
                float2 cB = cxy[(j + 32) * 64 + lane];
                float  zB = cz[(j + 32) * 64 + lane];
                float cw  = fmaf(cB.x, cB.x, fmaf(cB.y, cB.y, zB*zB));
                float dot = fmaf(qx, cB.x, fmaf(qy, cB.y, qz * zB));
                float d2  = fmaf(-2.0f, dot, s1 + cw);
                u32 u = __float_as_uint(d2);
                u32 key = u ^ (u32)(((int)u >> 31) | 0x80000000);
                keys[j + 32] = key;
                b3 = min(b3, key);
                u32 t;
                t = min(b2, b3); b3 = max(b2, b3); b2 = t;
                t = min(b1, b2); b2 = max(b1, b2); b1 = t;
                t = min(b0, b1); b1 = max(b0, b1); b0 = t;
            }
        }
        u32 k0 = a0, k1 = a1, k2 = a2, k3 = a3;
        #pragma unroll
        for (int m = 0; m < 4; ++m) {
            u32 x = (m == 0) ? b0 : (m == 1) ? b1 : (m == 2) ? b2 : b3;
            k3 = min(k3, x);
            u32 t;
            t = min(k2, k3); k3 = max(k2, k3); k2 = t;
            t = min(k1, k2); k2 = max(k1, k2); k1 = t;
            t = min(k0, k1); k1 = max(k0, k1); k0 = t;
        }

        // ---- phase B: bisect rank-31 threshold over kept-4 union ----
        u32 mn = k0, mx = k3;
        #pragma unroll
        for (int off = 1; off < 64; off <<= 1) {
            mn = min(mn, (u32)__shfl_xor((int)mn, off, 64));
            mx = max(mx, (u32)__shfl_xor((int)mx, off, 64));
        }
        u32 lo = mn, hi = mx;
        while (lo < hi) {
            u32 mid = lo + ((hi - lo) >> 1);
            int c = __popcll(__ballot(k0 <= mid)) + __popcll(__ballot(k1 <= mid))
                  + __popcll(__ballot(k2 <= mid)) + __popcll(__ballot(k3 <= mid));
            if (c >= 32) hi = mid; else lo = mid + 1;
        }
        u32 T = lo;

        // ---- phase C: certify (fast path when kept-4 provably complete) ----
        int nl;
        if (__ballot(k3 <= T) == 0ull) {
            nl = __popcll(__ballot(k0 < T)) + __popcll(__ballot(k1 < T))
               + __popcll(__ballot(k2 < T)) + __popcll(__ballot(k3 < T));
        } else {
            nl = 0;
            #pragma unroll
            for (int j = 0; j < 64; ++j) nl += __popcll(__ballot(keys[j] < T));
            if (nl > 31) {                  // kept-4 truncated (rare ~0.8%)
                lo = 0u; hi = T;
                while (lo < hi) {
                    u32 mid = lo + ((hi - lo) >> 1);
                    int c = 0;
                    #pragma unroll
                    for (int j = 0; j < 64; ++j) c += __popcll(__ballot(keys[j] <= mid));
                    if (c >= 32) hi = mid; else lo = mid + 1;
                }
                T = lo;
                nl = 0;
                #pragma unroll
                for (int j = 0; j < 64; ++j) nl += __popcll(__ballot(keys[j] < T));
            }
        }
        const int need_eq = 32 - nl;        // >= 1; ties resolved by candidate index

        // ---- phase D: emission via ballot prefix + fused moment accum ----
        float* fout = feats + ((size_t)(b * N_ + n) * KK_ + pr * KNN_) * 4;
        int base = 0, eq_seen = 0;
        #pragma unroll
        for (int j = 0; j < 64; ++j) {
            u32 key = keys[j];
            bool lt = key < T;
            bool eq = key == T;
            u64 mlt = __ballot(lt);
            u64 meq = __ballot(eq);
            if (mlt | meq) {
                int slot = -1;
                if (lt) slot = base + __popcll(mlt & below);
                else if (eq) {
                    int es = eq_seen + __popcll(meq & below);
                    if (es < need_eq) slot = nl + es;
                }
                if (slot >= 0) {
                    float2 cx2 = cxy[j * 64 + lane];
                    float  cz1 = cz[j * 64 + lane];
                    float rx = cx2.x - qx, ry = cx2.y - qy, rz = cz1 - qz;
                    float dist = sqrtf(fmaf(rx, rx, fmaf(ry, ry, rz*rz)));
                    *(float4*)(fout + slot * 4) = make_float4(rx, ry, rz, dist);
                    // fused feats moments (exactly once per feats entry)
                    mm[0] += rx; mm[1] += ry; mm[2] += rz; mm[3] += dist;
                    mm[4]  = fmaf(rx, rx, mm[4]);   mm[5]  = fmaf(rx, ry, mm[5]);
                    mm[6]  = fmaf(rx, rz, mm[6]);   mm[7]  = fmaf(rx, dist, mm[7]);
                    mm[8]  = fmaf(ry, ry, mm[8]);   mm[9]  = fmaf(ry, rz, mm[9]);
                    mm[10] = fmaf(ry, dist, mm[10]); mm[11] = fmaf(rz, rz, mm[11]);
                    mm[12] = fmaf(rz, dist, mm[12]); mm[13] = fmaf(dist, dist, mm[13]);
                }
                base    += __popcll(mlt);
                eq_seen += __popcll(meq);
            }
        }
    }

    // ---- block-level moment reduction -> 14 padded-cacheline atomics ----
    #pragma unroll
    for (int s = 0; s < 14; ++s) {
        #pragma unroll
        for (int off = 1; off < 64; off <<= 1) mm[s] += __shfl_xor(mm[s], off, 64);
    }
    if (lane == 0) {
        #pragma unroll
        for (int s = 0; s < 14; ++s) part[wave][s] = mm[s];
    }
    __syncthreads();
    if (tid < 14) {
        float v = part[0][tid] + part[1][tid] + part[2][tid] + part[3][tid];
        atomicAdd(&mom[tid * 16], v);    // one cacheline per counter
    }
}

// ---------------------------------------------------------------------------
// K3: MFMA conv2 (r9 structure): bn1 from moments, y2 -> bf16 y2F + stats2.
// ---------------------------------------------------------------------------
__global__ __launch_bounds__(256) void conv2_mfma(
    const float* __restrict__ feats,
    const float* __restrict__ W1,
    const float* __restrict__ g1, const float* __restrict__ be1,
    const float* __restrict__ W2,
    const float* __restrict__ mom,
    ushort* __restrict__ y2F, float* __restrict__ s2S, float* __restrict__ s2Q)
{
    __shared__ float statS[64], statQ[64];
    const int tid = threadIdx.x;
    const int wid = tid >> 6, l = tid & 63, q = l >> 4, i = l & 15;
    if (tid < 64) { statS[tid] = 0.f; statQ[tid] = 0.f; }

    const float invM = 1.0f / MTOT;
    const float M0 = mom[0*16], M1 = mom[1*16], M2 = mom[2*16], M3 = mom[3*16];
    const float Sxx = mom[4*16],  Sxy = mom[5*16],  Sxz = mom[6*16],  Sxd = mom[7*16];
    const float Syy = mom[8*16],  Syz = mom[9*16],  Syd = mom[10*16];
    const float Szz = mom[11*16], Szd = mom[12*16], Sdd = mom[13*16];

    float4 w1f[16];
    float  c1v[16];
    #pragma unroll
    for (int h = 0; h < 2; ++h)
      #pragma unroll
      for (int j = 0; j < 8; ++j) {
        int ci = h*32 + q*8 + j;
        float w0 = W1[ci*4+0], w1 = W1[ci*4+1], w2 = W1[ci*4+2], w3 = W1[ci*4+3];
        float meanf = (w0*M0 + w1*M1 + w2*M2 + w3*M3) * invM;
        float qq = w0*(w0*Sxx + 2.f*(w1*Sxy + w2*Sxz + w3*Sxd))
                 + w1*(w1*Syy + 2.f*(w2*Syz + w3*Syd))
                 + w2*(w2*Szz + 2.f*w3*Szd)
                 + w3*w3*Sdd;
        float var = qq * invM - meanf * meanf;
        float sc  = g1[ci] * rsqrtf(var + BN_EPS);
        w1f[h*8+j] = make_float4(sc*w0, sc*w1, sc*w2, sc*w3);
        c1v[h*8+j] = fmaf(-sc, meanf, be1[ci]);
      }
    bf16x8 a2[4][2];
    #pragma unroll
    for (int t = 0; t < 4; ++t)
      #pragma unroll
      for (int h = 0; h < 2; ++h)
        #pragma unroll
        for (int j = 0; j < 8; ++j)
          a2[t][h][j] = (short)f2bf_bits(W2[(t*16 + i)*64 + h*32 + q*8 + j]);

    float ssum[16], ssq[16];
    #pragma unroll
    for (int s = 0; s < 16; ++s) { ssum[s] = 0.f; ssq[s] = 0.f; }
    __syncthreads();

    for (int r16 = 0; r16 < 16; ++r16) {
        const int row = blockIdx.x * 16 + r16;
        float4 f = ((const float4*)feats)[row*64 + wid*16 + i];
        bf16x8 xb[2];
        #pragma unroll
        for (int h = 0; h < 2; ++h)
          #pragma unroll
          for (int j = 0; j < 8; ++j) {
            float4 w = w1f[h*8+j];
            float x = fmaxf(fmaf(w.x, f.x, fmaf(w.y, f.y, fmaf(w.z, f.z, fmaf(w.w, f.w, c1v[h*8+j])))), 0.f);
            xb[h][j] = (short)f2bf_bits(x);
          }
        f32x4 acc[4];
        #pragma unroll
        for (int t = 0; t < 4; ++t) acc[t] = (f32x4){0.f,0.f,0.f,0.f};
        #pragma unroll
        for (int t = 0; t < 4; ++t) {
            acc[t] = __builtin_amdgcn_mfma_f32_16x16x32_bf16(a2[t][0], xb[0], acc[t], 0, 0, 0);
            acc[t] = __builtin_amdgcn_mfma_f32_16x16x32_bf16(a2[t][1], xb[1], acc[t], 0, 0, 0);
        }
        ushort* wp = y2F + row*4096 + wid*1024 + q*64 + i*4;
        #pragma unroll
        for (int t = 0; t < 4; ++t) {
            #pragma unroll
            for (int reg = 0; reg < 4; ++reg) {
                float y = acc[t][reg];
                ssum[t*4+reg] += y;
                ssq[t*4+reg]  = fmaf(y, y, ssq[t*4+reg]);
            }
            uint2 pk;
            pk.x = (u32)f2bf_bits(acc[t][0]) | ((u32)f2bf_bits(acc[t][1]) << 16);
            pk.y = (u32)f2bf_bits(acc[t][2]) | ((u32)f2bf_bits(acc[t][3]) << 16);
            *(uint2*)(wp + t*256) = pk;
        }
    }
    #pragma unroll
    for (int s = 0; s < 16; ++s) {
        #pragma unroll
        for (int off = 1; off < 16; off <<= 1) {
            ssum[s] += __shfl_xor(ssum[s], off, 64);
            ssq[s]  += __shfl_xor(ssq[s],  off, 64);
        }
    }
    if (i == 0) {
        #pragma unroll
        for (int s = 0; s < 16; ++s) {
            int co = (s >> 2)*16 + q*4 + (s & 3);
            atomicAdd(&statS[co], ssum[s]);
            atomicAdd(&statQ[co], ssq[s]);
        }
    }
    __syncthreads();
    if (tid < 64) { atomicAdd(&s2S[tid], statS[tid]); atomicAdd(&s2Q[tid], statQ[tid]); }
}

// ---------------------------------------------------------------------------
// K4/K5: MFMA conv3 (r9 structure). FINAL reconstructs coords as q + resi.
// ---------------------------------------------------------------------------
template<bool FINAL>
__global__ __launch_bounds__(256) void conv3_mfma(
    const ushort* __restrict__ y2F,
    const float* __restrict__ g2, const float* __restrict__ be2,
    const float* __restrict__ W3,
    const float* __restrict__ g3, const float* __restrict__ be3,
    const float* __restrict__ s2S, const float* __restrict__ s2Q,
    float* __restrict__ s3S, float* __restrict__ s3Q,
    const float4* __restrict__ feats4, const float* __restrict__ p1,
    float* __restrict__ outp)
{
    __shared__ float statS[128], statQ[128];
    __shared__ float sc3L[128], sh3L[128];
    __shared__ float scoreL[2][64];

    const int tid = threadIdx.x;
    const int wid = tid >> 6, l = tid & 63, q = l >> 4, i = l & 15;

    if (!FINAL) {
        if (tid < 128) { statS[tid] = 0.f; statQ[tid] = 0.f; }
    } else if (tid < 128) {
        float m  = s3S[tid] * (1.0f / MTOT);
        float v  = s3Q[tid] * (1.0f / MTOT) - m * m;
        float sc = g3[tid] * rsqrtf(v + BN_EPS);
        sc3L[tid] = sc;
        sh3L[tid] = fmaf(-sc, m, be3[tid]);
    }

    float sc2v[16], sh2v[16];
    #pragma unroll
    for (int h = 0; h < 2; ++h)
      #pragma unroll
      for (int j = 0; j < 8; ++j) {
        int ci = h*32 + q*8 + j;
        float m  = s2S[ci] * (1.0f / MTOT);
        float v  = s2Q[ci] * (1.0f / MTOT) - m * m;
        float sc = g2[ci] * rsqrtf(v + BN_EPS);
        sc2v[h*8+j] = sc;
        sh2v[h*8+j] = fmaf(-sc, m, be2[ci]);
      }
    bf16x8 a3[8][2];
    #pragma unroll
    for (int t = 0; t < 8; ++t)
      #pragma unroll
      for (int h = 0; h < 2; ++h)
        #pragma unroll
        for (int j = 0; j < 8; ++j)
          a3[t][h][j] = (short)f2bf_bits(W3[(t*16 + i)*64 + h*32 + q*8 + j]);

    float ssum[32], ssq[32];
    if (!FINAL) {
        #pragma unroll
        for (int s = 0; s < 32; ++s) { ssum[s] = 0.f; ssq[s] = 0.f; }
    }
    __syncthreads();

    for (int r16 = 0; r16 < 16; ++r16) {
        const int row = blockIdx.x * 16 + r16;
        const ushort* rp = y2F + row*4096 + wid*1024 + q*128 + i*4;
        uint2 u00 = *(const uint2*)(rp);
        uint2 u01 = *(const uint2*)(rp + 64);
        uint2 u10 = *(const uint2*)(rp + 512);
        uint2 u11 = *(const uint2*)(rp + 576);

        bf16x8 xb[2];
        #pragma unroll
        for (int h = 0; h < 2; ++h) {
            u32 w0 = (h == 0) ? u00.x : u10.x;
            u32 w1 = (h == 0) ? u00.y : u10.y;
            u32 w2 = (h == 0) ? u01.x : u11.x;
            u32 w3 = (h == 0) ? u01.y : u11.y;
            float xf[8];
            xf[0] = __uint_as_float(w0 << 16); xf[1] = __uint_as_float(w0 & 0xffff0000u);
            xf[2] = __uint_as_float(w1 << 16); xf[3] = __uint_as_float(w1 & 0xffff0000u);
            xf[4] = __uint_as_float(w2 << 16); xf[5] = __uint_as_float(w2 & 0xffff0000u);
            xf[6] = __uint_as_float(w3 << 16); xf[7] = __uint_as_float(w3 & 0xffff0000u);
            #pragma unroll
            for (int j = 0; j < 8; ++j) {
                float x = fmaxf(fmaf(sc2v[h*8+j], xf[j], sh2v[h*8+j]), 0.f);
                xb[h][j] = (short)f2bf_bits(x);
            }
        }
        f32x4 acc[8];
        #pragma unroll
        for (int t = 0; t < 8; ++t) acc[t] = (f32x4){0.f,0.f,0.f,0.f};
        #pragma unroll
        for (int t = 0; t < 8; ++t) {
            acc[t] = __builtin_amdgcn_mfma_f32_16x16x32_bf16(a3[t][0], xb[0], acc[t], 0, 0, 0);
            acc[t] = __builtin_amdgcn_mfma_f32_16x16x32_bf16(a3[t][1], xb[1], acc[t], 0, 0, 0);
        }

        if (!FINAL) {
            #pragma unroll
            for (int t = 0; t < 8; ++t)
              #pragma unroll
              for (int reg = 0; reg < 4; ++reg) {
                float y = acc[t][reg];
                ssum[t*4+reg] += y;
                ssq[t*4+reg]  = fmaf(y, y, ssq[t*4+reg]);
              }
        } else {
            float mx = -3.4e38f;
            #pragma unroll
            for (int t = 0; t < 8; ++t) {
                float4 s4 = *(const float4*)&sc3L[t*16 + q*4];
                float4 h4 = *(const float4*)&sh3L[t*16 + q*4];
                mx = fmaxf(mx, fmaf(s4.x, acc[t][0], h4.x));
                mx = fmaxf(mx, fmaf(s4.y, acc[t][1], h4.y));
                mx = fmaxf(mx, fmaf(s4.z, acc[t][2], h4.z));
                mx = fmaxf(mx, fmaf(s4.w, acc[t][3], h4.w));
            }
            mx = fmaxf(mx, __shfl_xor(mx, 16, 64));
            mx = fmaxf(mx, __shfl_xor(mx, 32, 64));
            mx = fmaxf(mx, 0.f);
            if (q == 0) scoreL[r16 & 1][wid*16 + i] = mx;
            __syncthreads();
            if (wid == 0) {
                float sc = scoreL[r16 & 1][l];
                float m2 = sc;
                #pragma unroll
                for (int off = 1; off < 64; off <<= 1) m2 = fmaxf(m2, __shfl_xor(m2, off, 64));
                float e = __expf(sc - m2);
                float se = e;
                #pragma unroll
                for (int off = 1; off < 64; off <<= 1) se += __shfl_xor(se, off, 64);
                float w = e / se;
                const int bb = row >> 12, n = row & 4095;
                float qx = p1[(size_t)bb*3*N_ + n];
                float qy = p1[(size_t)bb*3*N_ + N_ + n];
                float qz = p1[(size_t)bb*3*N_ + 2*N_ + n];
                float4 f4 = feats4[row*64 + l];
                float ox = w * (f4.x + qx), oy = w * (f4.y + qy), oz = w * (f4.z + qz);
                #pragma unroll
                for (int off = 1; off < 64; off <<= 1) {
                    ox += __shfl_xor(ox, off, 64);
                    oy += __shfl_xor(oy, off, 64);
                    oz += __shfl_xor(oz, off, 64);
                }
                if (l == 0) {
                    outp[bb*3*N_ + 0*N_ + n] = ox;
                    outp[bb*3*N_ + 1*N_ + n] = oy;
                    outp[bb*3*N_ + 2*N_ + n] = oz;
                }
            }
        }
    }

    if (!FINAL) {
        #pragma unroll
        for (int s = 0; s < 32; ++s) {
            #pragma unroll
            for (int off = 1; off < 16; off <<= 1) {
                ssum[s] += __shfl_xor(ssum[s], off, 64);
                ssq[s]  += __shfl_xor(ssq[s],  off, 64);
            }
        }
        if (i == 0) {
            #pragma unroll
            for (int s = 0; s < 32; ++s) {
                int co = (s >> 2)*16 + q*4 + (s & 3);
                atomicAdd(&statS[co], ssum[s]);
                atomicAdd(&statQ[co], ssq[s]);
            }
        }
        __syncthreads();
        if (tid < 128) { atomicAdd(&s3S[tid], statS[tid]); atomicAdd(&s3Q[tid], statQ[tid]); }
    }
}

// ---------------------------------------------------------------------------
extern "C" void kernel_launch(void* const* d_in, const int* in_sizes, int n_in,
                              void* d_out, int out_size, void* d_ws, size_t ws_size,
                              hipStream_t stream)
{
    const float* p1  = (const float*)d_in[0];
    const float* p2  = (const float*)d_in[1];
    // d_in[2] = k (always 32), d_in[3] = t (unused by reference)
    const float* W1  = (const float*)d_in[4];
    const float* g1  = (const float*)d_in[6];
    const float* be1 = (const float*)d_in[7];
    const float* W2  = (const float*)d_in[8];
    const float* g2  = (const float*)d_in[10];
    const float* be2 = (const float*)d_in[11];
    const float* W3  = (const float*)d_in[12];
    const float* g3  = (const float*)d_in[14];
    const float* be3 = (const float*)d_in[15];
    // b1 cancels through bn1 (moment fold); b2/b3 cancel through bn2/bn3.

    char* ws = (char*)d_ws;
    const size_t OFF_FEATS = 4096;
    const size_t OFF_Y2    = OFF_FEATS + (size_t)MTOT * 4 * 4;          // 16 MB feats
    const size_t NEEDED    = OFF_Y2 + (size_t)MTOT * 64 * 2;            // 128 MB y2 bf16
    if (ws_size < NEEDED) return;  // fail visibly (wrong output) rather than fault

    float* s2S = (float*)(ws + 512);  float* s2Q = (float*)(ws + 768);
    float* s3S = (float*)(ws + 1024); float* s3Q = (float*)(ws + 1536);
    float* mom = (float*)(ws + 2048);            // 14 counters, 64-B stride each
    float* feats = (float*)(ws + OFF_FEATS);
    ushort* y2F  = (ushort*)(ws + OFF_Y2);

    hipMemsetAsync(ws, 0, 4096, stream);  // zero stats + padded moment counters

    knn_kernel<<<768, 256, 0, stream>>>(p1, p2, feats, mom);
    conv2_mfma<<<1024, 256, 0, stream>>>(feats, W1, g1, be1, W2, mom,
                                         y2F, s2S, s2Q);
    conv3_mfma<false><<<1024, 256, 0, stream>>>(y2F, g2, be2, W3, g3, be3,
                                                s2S, s2Q, s3S, s3Q,
                                                nullptr, nullptr, nullptr);
    conv3_mfma<true><<<1024, 256, 0, stream>>>(y2F, g2, be2, W3, g3, be3,
                                               s2S, s2Q, s3S, s3Q,
                                               (const float4*)feats, p1,
                                               (float*)d_out);
}

// Round 13
// 477.360 us; speedup vs baseline: 1.3391x; 1.0721x over previous
//
#include <hip/hip_runtime.h>
#include <hip/hip_bf16.h>

// Problem constants (fixed by setup_inputs)
#define B_   4
#define N_   4096
#define KNN_ 32
#define KK_  64          // 2*k
#define MTOT 1048576     // B*N*KK
#define BN_EPS 1e-3f

typedef unsigned int u32;
typedef unsigned long long u64;
typedef __attribute__((ext_vector_type(8))) short bf16x8;
typedef __attribute__((ext_vector_type(4))) float f32x4;

__device__ __forceinline__ ushort f2bf_bits(float f) {   // RNE, finite inputs only
    u32 b = __float_as_uint(f);
    b += 0x7fffu + ((b >> 16) & 1u);
    return (ushort)(b >> 16);
}

// ---------------------------------------------------------------------------
// K1: dual KNN, atomic-free (r12: keys in registers, split kept-4 chains,
// fused feats-moment accumulation with padded-cacheline atomics).
// grid: 768 blocks = 8 (pr,b) * 96 chunks; 4 waves stride.
// ---------------------------------------------------------------------------
__global__ __launch_bounds__(256, 3) void knn_kernel(
    const float* __restrict__ p1, const float* __restrict__ p2,
    float* __restrict__ feats, float* __restrict__ mom)
{
    __shared__ float2 cxy[N_];                   // 32 KB
    __shared__ float  cz[N_];                    // 16 KB
    __shared__ float  part[4][14];

    const int tid  = threadIdx.x;
    const int wave = tid >> 6, lane = tid & 63;
    const int pb    = blockIdx.x / 96;           // 0..7
    const int chunk = blockIdx.x % 96;
    const int pr = pb >> 2, b = pb & 3;
    const int start = (chunk * 4096) / 96;
    const int end   = ((chunk + 1) * 4096) / 96;

    const float* srcb = (pr ? p2 : p1) + (size_t)b * 3 * N_;
    for (int n = tid; n < N_; n += 256) {
        float x = srcb[n], y = srcb[N_ + n], z = srcb[2*N_ + n];
        cxy[n] = make_float2(x, y);
        cz[n]  = z;
    }
    __syncthreads();

    const float* p1b = p1 + (size_t)b * 3 * N_;
    const u64 below = (1ull << lane) - 1ull;

    float mm[14];
    #pragma unroll
    for (int s = 0; s < 14; ++s) mm[s] = 0.f;

    for (int n = start + wave; n < end; n += 4) {
        float qx, qy, qz;
        if (pr == 0) { float2 q = cxy[n]; qx = q.x; qy = q.y; qz = cz[n]; }
        else         { qx = p1b[n]; qy = p1b[N_ + n]; qz = p1b[2*N_ + n]; }
        const float s1 = fmaf(qx, qx, fmaf(qy, qy, qz*qz));

        // ---- phase A: keys (once, registers) + two independent kept-4 ----
        u32 keys[64];
        u32 a0 = 0xFFFFFFFFu, a1 = 0xFFFFFFFFu, a2 = 0xFFFFFFFFu, a3 = 0xFFFFFFFFu;
        u32 b0 = 0xFFFFFFFFu, b1 = 0xFFFFFFFFu, b2 = 0xFFFFFFFFu, b3 = 0xFFFFFFFFu;
        #pragma unroll
        for (int j = 0; j < 32; ++j) {
            {
                float2 cA = cxy[j * 64 + lane];
                float  zA = cz[j * 64 + lane];
                float cw  = fmaf(cA.x, cA.x, fmaf(cA.y, cA.y, zA*zA));
                float dot = fmaf(qx, cA.x, fmaf(qy, cA.y, qz * zA));
                float d2  = fmaf(-2.0f, dot, s1 + cw);
                u32 u = __float_as_uint(d2);
                u32 key = u ^ (u32)(((int)u >> 31) | 0x80000000);
                keys[j] = key;
                a3 = min(a3, key);
                u32 t;
                t = min(a2, a3); a3 = max(a2, a3); a2 = t;
                t = min(a1, a2); a2 = max(a1, a2); a1 = t;
                t = min(a0, a1); a1 = max(a0, a1); a0 = t;
            }
            {
                float2 cB = cxy[(j + 32) * 64 + lane];
                float  zB = cz[(j + 32) * 64 + lane];
                float cw  = fmaf(cB.x, cB.x, fmaf(cB.y, cB.y, zB*zB));
                float dot = fmaf(qx, cB.x, fmaf(qy, cB.y, qz * zB));
                float d2  = fmaf(-2.0f, dot, s1 + cw);
                u32 u = __float_as_uint(d2);
                u32 key = u ^ (u32)(((int)u >> 31) | 0x80000000);
                keys[j + 32] = key;
                b3 = min(b3, key);
                u32 t;
                t = min(b2, b3); b3 = max(b2, b3); b2 = t;
                t = min(b1, b2); b2 = max(b1, b2); b1 = t;
                t = min(b0, b1); b1 = max(b0, b1); b0 = t;
            }
        }
        u32 k0 = a0, k1 = a1, k2 = a2, k3 = a3;
        #pragma unroll
        for (int m = 0; m < 4; ++m) {
            u32 x = (m == 0) ? b0 : (m == 1) ? b1 : (m == 2) ? b2 : b3;
            k3 = min(k3, x);
            u32 t;
            t = min(k2, k3); k3 = max(k2, k3); k2 = t;
            t = min(k1, k2); k2 = max(k1, k2); k1 = t;
            t = min(k0, k1); k1 = max(k0, k1); k0 = t;
        }

        // ---- phase B: bisect rank-31 threshold over kept-4 union ----
        u32 mn = k0, mx = k3;
        #pragma unroll
        for (int off = 1; off < 64; off <<= 1) {
            mn = min(mn, (u32)__shfl_xor((int)mn, off, 64));
            mx = max(mx, (u32)__shfl_xor((int)mx, off, 64));
        }
        u32 lo = mn, hi = mx;
        while (lo < hi) {
            u32 mid = lo + ((hi - lo) >> 1);
            int c = __popcll(__ballot(k0 <= mid)) + __popcll(__ballot(k1 <= mid))
                  + __popcll(__ballot(k2 <= mid)) + __popcll(__ballot(k3 <= mid));
            if (c >= 32) hi = mid; else lo = mid + 1;
        }
        u32 T = lo;

        // ---- phase C: certify (fast path when kept-4 provably complete) ----
        int nl;
        if (__ballot(k3 <= T) == 0ull) {
            nl = __popcll(__ballot(k0 < T)) + __popcll(__ballot(k1 < T))
               + __popcll(__ballot(k2 < T)) + __popcll(__ballot(k3 < T));
        } else {
            nl = 0;
            #pragma unroll
            for (int j = 0; j < 64; ++j) nl += __popcll(__ballot(keys[j] < T));
            if (nl > 31) {                  // kept-4 truncated (rare ~0.8%)
                lo = 0u; hi = T;
                while (lo < hi) {
                    u32 mid = lo + ((hi - lo) >> 1);
                    int c = 0;
                    #pragma unroll
                    for (int j = 0; j < 64; ++j) c += __popcll(__ballot(keys[j] <= mid));
                    if (c >= 32) hi = mid; else lo = mid + 1;
                }
                T = lo;
                nl = 0;
                #pragma unroll
                for (int j = 0; j < 64; ++j) nl += __popcll(__ballot(keys[j] < T));
            }
        }
        const int need_eq = 32 - nl;        // >= 1; ties resolved by candidate index

        // ---- phase D: emission via ballot prefix + fused moment accum ----
        float* fout = feats + ((size_t)(b * N_ + n) * KK_ + pr * KNN_) * 4;
        int base = 0, eq_seen = 0;
        #pragma unroll
        for (int j = 0; j < 64; ++j) {
            u32 key = keys[j];
            bool lt = key < T;
            bool eq = key == T;
            u64 mlt = __ballot(lt);
            u64 meq = __ballot(eq);
            if (mlt | meq) {
                int slot = -1;
                if (lt) slot = base + __popcll(mlt & below);
                else if (eq) {
                    int es = eq_seen + __popcll(meq & below);
                    if (es < need_eq) slot = nl + es;
                }
                if (slot >= 0) {
                    float2 cx2 = cxy[j * 64 + lane];
                    float  cz1 = cz[j * 64 + lane];
                    float rx = cx2.x - qx, ry = cx2.y - qy, rz = cz1 - qz;
                    float dist = sqrtf(fmaf(rx, rx, fmaf(ry, ry, rz*rz)));
                    *(float4*)(fout + slot * 4) = make_float4(rx, ry, rz, dist);
                    mm[0] += rx; mm[1] += ry; mm[2] += rz; mm[3] += dist;
                    mm[4]  = fmaf(rx, rx, mm[4]);   mm[5]  = fmaf(rx, ry, mm[5]);
                    mm[6]  = fmaf(rx, rz, mm[6]);   mm[7]  = fmaf(rx, dist, mm[7]);
                    mm[8]  = fmaf(ry, ry, mm[8]);   mm[9]  = fmaf(ry, rz, mm[9]);
                    mm[10] = fmaf(ry, dist, mm[10]); mm[11] = fmaf(rz, rz, mm[11]);
                    mm[12] = fmaf(rz, dist, mm[12]); mm[13] = fmaf(dist, dist, mm[13]);
                }
                base    += __popcll(mlt);
                eq_seen += __popcll(meq);
            }
        }
    }

    #pragma unroll
    for (int s = 0; s < 14; ++s) {
        #pragma unroll
        for (int off = 1; off < 64; off <<= 1) mm[s] += __shfl_xor(mm[s], off, 64);
    }
    if (lane == 0) {
        #pragma unroll
        for (int s = 0; s < 14; ++s) part[wave][s] = mm[s];
    }
    __syncthreads();
    if (tid < 14) {
        float v = part[0][tid] + part[1][tid] + part[2][tid] + part[3][tid];
        atomicAdd(&mom[tid * 16], v);    // one cacheline per counter
    }
}

// ---------------------------------------------------------------------------
// K3: MFMA conv2 (r12): bn1 from moments, y2 -> bf16 y2F + stats2.
// ---------------------------------------------------------------------------
__global__ __launch_bounds__(256) void conv2_mfma(
    const float* __restrict__ feats,
    const float* __restrict__ W1,
    const float* __restrict__ g1, const float* __restrict__ be1,
    const float* __restrict__ W2,
    const float* __restrict__ mom,
    ushort* __restrict__ y2F, float* __restrict__ s2S, float* __restrict__ s2Q)
{
    __shared__ float statS[64], statQ[64];
    const int tid = threadIdx.x;
    const int wid = tid >> 6, l = tid & 63, q = l >> 4, i = l & 15;
    if (tid < 64) { statS[tid] = 0.f; statQ[tid] = 0.f; }

    const float invM = 1.0f / MTOT;
    const float M0 = mom[0*16], M1 = mom[1*16], M2 = mom[2*16], M3 = mom[3*16];
    const float Sxx = mom[4*16],  Sxy = mom[5*16],  Sxz = mom[6*16],  Sxd = mom[7*16];
    const float Syy = mom[8*16],  Syz = mom[9*16],  Syd = mom[10*16];
    const float Szz = mom[11*16], Szd = mom[12*16], Sdd = mom[13*16];

    float4 w1f[16];
    float  c1v[16];
    #pragma unroll
    for (int h = 0; h < 2; ++h)
      #pragma unroll
      for (int j = 0; j < 8; ++j) {
        int ci = h*32 + q*8 + j;
        float w0 = W1[ci*4+0], w1 = W1[ci*4+1], w2 = W1[ci*4+2], w3 = W1[ci*4+3];
        float meanf = (w0*M0 + w1*M1 + w2*M2 + w3*M3) * invM;
        float qq = w0*(w0*Sxx + 2.f*(w1*Sxy + w2*Sxz + w3*Sxd))
                 + w1*(w1*Syy + 2.f*(w2*Syz + w3*Syd))
                 + w2*(w2*Szz + 2.f*w3*Szd)
                 + w3*w3*Sdd;
        float var = qq * invM - meanf * meanf;
        float sc  = g1[ci] * rsqrtf(var + BN_EPS);
        w1f[h*8+j] = make_float4(sc*w0, sc*w1, sc*w2, sc*w3);
        c1v[h*8+j] = fmaf(-sc, meanf, be1[ci]);
      }
    bf16x8 a2[4][2];
    #pragma unroll
    for (int t = 0; t < 4; ++t)
      #pragma unroll
      for (int h = 0; h < 2; ++h)
        #pragma unroll
        for (int j = 0; j < 8; ++j)
          a2[t][h][j] = (short)f2bf_bits(W2[(t*16 + i)*64 + h*32 + q*8 + j]);

    float ssum[16], ssq[16];
    #pragma unroll
    for (int s = 0; s < 16; ++s) { ssum[s] = 0.f; ssq[s] = 0.f; }
    __syncthreads();

    for (int r16 = 0; r16 < 16; ++r16) {
        const int row = blockIdx.x * 16 + r16;
        float4 f = ((const float4*)feats)[row*64 + wid*16 + i];
        bf16x8 xb[2];
        #pragma unroll
        for (int h = 0; h < 2; ++h)
          #pragma unroll
          for (int j = 0; j < 8; ++j) {
            float4 w = w1f[h*8+j];
            float x = fmaxf(fmaf(w.x, f.x, fmaf(w.y, f.y, fmaf(w.z, f.z, fmaf(w.w, f.w, c1v[h*8+j])))), 0.f);
            xb[h][j] = (short)f2bf_bits(x);
          }
        f32x4 acc[4];
        #pragma unroll
        for (int t = 0; t < 4; ++t) acc[t] = (f32x4){0.f,0.f,0.f,0.f};
        #pragma unroll
        for (int t = 0; t < 4; ++t) {
            acc[t] = __builtin_amdgcn_mfma_f32_16x16x32_bf16(a2[t][0], xb[0], acc[t], 0, 0, 0);
            acc[t] = __builtin_amdgcn_mfma_f32_16x16x32_bf16(a2[t][1], xb[1], acc[t], 0, 0, 0);
        }
        ushort* wp = y2F + row*4096 + wid*1024 + q*64 + i*4;
        #pragma unroll
        for (int t = 0; t < 4; ++t) {
            #pragma unroll
            for (int reg = 0; reg < 4; ++reg) {
                float y = acc[t][reg];
                ssum[t*4+reg] += y;
                ssq[t*4+reg]  = fmaf(y, y, ssq[t*4+reg]);
            }
            uint2 pk;
            pk.x = (u32)f2bf_bits(acc[t][0]) | ((u32)f2bf_bits(acc[t][1]) << 16);
            pk.y = (u32)f2bf_bits(acc[t][2]) | ((u32)f2bf_bits(acc[t][3]) << 16);
            *(uint2*)(wp + t*256) = pk;
        }
    }
    #pragma unroll
    for (int s = 0; s < 16; ++s) {
        #pragma unroll
        for (int off = 1; off < 16; off <<= 1) {
            ssum[s] += __shfl_xor(ssum[s], off, 64);
            ssq[s]  += __shfl_xor(ssq[s],  off, 64);
        }
    }
    if (i == 0) {
        #pragma unroll
        for (int s = 0; s < 16; ++s) {
            int co = (s >> 2)*16 + q*4 + (s & 3);
            atomicAdd(&statS[co], ssum[s]);
            atomicAdd(&statQ[co], ssq[s]);
        }
    }
    __syncthreads();
    if (tid < 64) { atomicAdd(&s2S[tid], statS[tid]); atomicAdd(&s2Q[tid], statQ[tid]); }
}

// ---------------------------------------------------------------------------
// K4: conv3 stats pass, wave-split by (pos-half ph, out-ch-half oh).
// Reads y2 frags, builds x3 = relu(bn2(y2)) (bit-identical to r12), writes
// x3 back IN PLACE over y2F (oh==0 waves; per-row barrier makes it race-free),
// accumulates stats3 for its 64-channel half.
// ---------------------------------------------------------------------------
__global__ __launch_bounds__(256) void conv3_stats(
    ushort* __restrict__ y2F,
    const float* __restrict__ g2, const float* __restrict__ be2,
    const float* __restrict__ W3,
    const float* __restrict__ s2S, const float* __restrict__ s2Q,
    float* __restrict__ s3S, float* __restrict__ s3Q)
{
    __shared__ float statS[128], statQ[128];
    const int tid = threadIdx.x;
    const int w = tid >> 6, l = tid & 63, q = l >> 4, i = l & 15;
    const int ph = w >> 1, oh = w & 1;
    if (tid < 128) { statS[tid] = 0.f; statQ[tid] = 0.f; }

    float sc2v[16], sh2v[16];
    #pragma unroll
    for (int h = 0; h < 2; ++h)
      #pragma unroll
      for (int j = 0; j < 8; ++j) {
        int ci = h*32 + q*8 + j;
        float m  = s2S[ci] * (1.0f / MTOT);
        float v  = s2Q[ci] * (1.0f / MTOT) - m * m;
        float sc = g2[ci] * rsqrtf(v + BN_EPS);
        sc2v[h*8+j] = sc;
        sh2v[h*8+j] = fmaf(-sc, m, be2[ci]);
      }
    bf16x8 a3[4][2];
    #pragma unroll
    for (int t = 0; t < 4; ++t)
      #pragma unroll
      for (int h = 0; h < 2; ++h)
        #pragma unroll
        for (int j = 0; j < 8; ++j)
          a3[t][h][j] = (short)f2bf_bits(W3[((oh*4 + t)*16 + i)*64 + h*32 + q*8 + j]);

    float ssum[16], ssq[16];
    #pragma unroll
    for (int s = 0; s < 16; ++s) { ssum[s] = 0.f; ssq[s] = 0.f; }

    for (int r16 = 0; r16 < 16; ++r16) {
        const int row = blockIdx.x * 16 + r16;
        ushort* rp0 = y2F + row*4096 + (2*ph)*1024 + q*128 + i*4;
        ushort* rp1 = rp0 + 1024;
        uint2 a00 = *(const uint2*)(rp0);       uint2 a01 = *(const uint2*)(rp0 + 64);
        uint2 a10 = *(const uint2*)(rp0 + 512); uint2 a11 = *(const uint2*)(rp0 + 576);
        uint2 b00 = *(const uint2*)(rp1);       uint2 b01 = *(const uint2*)(rp1 + 64);
        uint2 b10 = *(const uint2*)(rp1 + 512); uint2 b11 = *(const uint2*)(rp1 + 576);

        bf16x8 xa[2], xc[2];
        #pragma unroll
        for (int pt2 = 0; pt2 < 2; ++pt2) {
            uint2 v00 = pt2 ? b00 : a00, v01 = pt2 ? b01 : a01;
            uint2 v10 = pt2 ? b10 : a10, v11 = pt2 ? b11 : a11;
            bf16x8* dst = pt2 ? xc : xa;
            #pragma unroll
            for (int h = 0; h < 2; ++h) {
                u32 w0 = h ? v10.x : v00.x, w1 = h ? v10.y : v00.y;
                u32 w2 = h ? v11.x : v01.x, w3 = h ? v11.y : v01.y;
                float xf[8];
                xf[0] = __uint_as_float(w0 << 16); xf[1] = __uint_as_float(w0 & 0xffff0000u);
                xf[2] = __uint_as_float(w1 << 16); xf[3] = __uint_as_float(w1 & 0xffff0000u);
                xf[4] = __uint_as_float(w2 << 16); xf[5] = __uint_as_float(w2 & 0xffff0000u);
                xf[6] = __uint_as_float(w3 << 16); xf[7] = __uint_as_float(w3 & 0xffff0000u);
                #pragma unroll
                for (int j = 0; j < 8; ++j) {
                    float x = fmaxf(fmaf(sc2v[h*8+j], xf[j], sh2v[h*8+j]), 0.f);
                    dst[h][j] = (short)f2bf_bits(x);
                }
            }
        }
        __syncthreads();     // all reads of this row drained before overwrite
        if (oh == 0) {       // in-place x3 write (frag layout preserved)
            uint4 ua0 = *(uint4*)&xa[0], ua1 = *(uint4*)&xa[1];
            uint4 uc0 = *(uint4*)&xc[0], uc1 = *(uint4*)&xc[1];
            *(uint2*)(rp0)       = make_uint2(ua0.x, ua0.y);
            *(uint2*)(rp0 + 64)  = make_uint2(ua0.z, ua0.w);
            *(uint2*)(rp0 + 512) = make_uint2(ua1.x, ua1.y);
            *(uint2*)(rp0 + 576) = make_uint2(ua1.z, ua1.w);
            *(uint2*)(rp1)       = make_uint2(uc0.x, uc0.y);
            *(uint2*)(rp1 + 64)  = make_uint2(uc0.z, uc0.w);
            *(uint2*)(rp1 + 512) = make_uint2(uc1.x, uc1.y);
            *(uint2*)(rp1 + 576) = make_uint2(uc1.z, uc1.w);
        }
        #pragma unroll
        for (int t = 0; t < 4; ++t) {
            f32x4 A = (f32x4){0.f,0.f,0.f,0.f};
            A = __builtin_amdgcn_mfma_f32_16x16x32_bf16(a3[t][0], xa[0], A, 0, 0, 0);
            A = __builtin_amdgcn_mfma_f32_16x16x32_bf16(a3[t][1], xa[1], A, 0, 0, 0);
            f32x4 Bv = (f32x4){0.f,0.f,0.f,0.f};
            Bv = __builtin_amdgcn_mfma_f32_16x16x32_bf16(a3[t][0], xc[0], Bv, 0, 0, 0);
            Bv = __builtin_amdgcn_mfma_f32_16x16x32_bf16(a3[t][1], xc[1], Bv, 0, 0, 0);
            #pragma unroll
            for (int reg = 0; reg < 4; ++reg) {
                float ya = A[reg], yb = Bv[reg];
                ssum[t*4+reg] += ya + yb;
                ssq[t*4+reg]  = fmaf(ya, ya, fmaf(yb, yb, ssq[t*4+reg]));
            }
        }
    }
    #pragma unroll
    for (int s = 0; s < 16; ++s) {
        #pragma unroll
        for (int off = 1; off < 16; off <<= 1) {
            ssum[s] += __shfl_xor(ssum[s], off, 64);
            ssq[s]  += __shfl_xor(ssq[s],  off, 64);
        }
    }
    if (i == 0) {
        #pragma unroll
        for (int s = 0; s < 16; ++s) {
            int co = oh*64 + (s >> 2)*16 + q*4 + (s & 3);
            atomicAdd(&statS[co], ssum[s]);
            atomicAdd(&statQ[co], ssq[s]);
        }
    }
    __syncthreads();
    if (tid < 128) { atomicAdd(&s3S[tid], statS[tid]); atomicAdd(&s3Q[tid], statQ[tid]); }
}

// ---------------------------------------------------------------------------
// K5: conv3 final pass, wave-split. Reads x3F frags DIRECTLY (zero repack),
// bn3 -> per-half channel max -> LDS combine -> softmax -> weighted sum.
// ---------------------------------------------------------------------------
__global__ __launch_bounds__(256) void conv3_final(
    const ushort* __restrict__ x3F,
    const float* __restrict__ W3,
    const float* __restrict__ g3, const float* __restrict__ be3,
    const float* __restrict__ s3S, const float* __restrict__ s3Q,
    const float4* __restrict__ feats4, const float* __restrict__ p1,
    float* __restrict__ outp)
{
    __shared__ float sc3L[128], sh3L[128];
    __shared__ float s2L[2][2][64];   // [row parity][oh][position]
    const int tid = threadIdx.x;
    const int w = tid >> 6, l = tid & 63, q = l >> 4, i = l & 15;
    const int ph = w >> 1, oh = w & 1;

    if (tid < 128) {
        float m  = s3S[tid] * (1.0f / MTOT);
        float v  = s3Q[tid] * (1.0f / MTOT) - m * m;
        float sc = g3[tid] * rsqrtf(v + BN_EPS);
        sc3L[tid] = sc;
        sh3L[tid] = fmaf(-sc, m, be3[tid]);
    }
    bf16x8 a3[4][2];
    #pragma unroll
    for (int t = 0; t < 4; ++t)
      #pragma unroll
      for (int h = 0; h < 2; ++h)
        #pragma unroll
        for (int j = 0; j < 8; ++j)
          a3[t][h][j] = (short)f2bf_bits(W3[((oh*4 + t)*16 + i)*64 + h*32 + q*8 + j]);
    __syncthreads();

    for (int r16 = 0; r16 < 16; ++r16) {
        const int row = blockIdx.x * 16 + r16;
        #pragma unroll
        for (int pt2 = 0; pt2 < 2; ++pt2) {
            const int pt = 2*ph + pt2;
            const ushort* rp = x3F + row*4096 + pt*1024 + q*128 + i*4;
            uint2 u00 = *(const uint2*)(rp);       uint2 u01 = *(const uint2*)(rp + 64);
            uint2 u10 = *(const uint2*)(rp + 512); uint2 u11 = *(const uint2*)(rp + 576);
            uint4 v0 = make_uint4(u00.x, u00.y, u01.x, u01.y);
            uint4 v1 = make_uint4(u10.x, u10.y, u11.x, u11.y);
            bf16x8 xb0 = *(bf16x8*)&v0, xb1 = *(bf16x8*)&v1;
            float mx = -3.4e38f;
            #pragma unroll
            for (int t = 0; t < 4; ++t) {
                f32x4 a = (f32x4){0.f,0.f,0.f,0.f};
                a = __builtin_amdgcn_mfma_f32_16x16x32_bf16(a3[t][0], xb0, a, 0, 0, 0);
                a = __builtin_amdgcn_mfma_f32_16x16x32_bf16(a3[t][1], xb1, a, 0, 0, 0);
                const int co = oh*64 + t*16 + q*4;
                float4 s4 = *(const float4*)&sc3L[co];
                float4 h4 = *(const float4*)&sh3L[co];
                mx = fmaxf(mx, fmaf(s4.x, a[0], h4.x));
                mx = fmaxf(mx, fmaf(s4.y, a[1], h4.y));
                mx = fmaxf(mx, fmaf(s4.z, a[2], h4.z));
                mx = fmaxf(mx, fmaf(s4.w, a[3], h4.w));
            }
            mx = fmaxf(mx, __shfl_xor(mx, 16, 64));
            mx = fmaxf(mx, __shfl_xor(mx, 32, 64));
            if (q == 0) s2L[r16 & 1][oh][pt*16 + i] = mx;
        }
        __syncthreads();
        if (w == 0) {
            float sc = fmaxf(fmaxf(s2L[r16 & 1][0][l], s2L[r16 & 1][1][l]), 0.f);
            float m2 = sc;
            #pragma unroll
            for (int off = 1; off < 64; off <<= 1) m2 = fmaxf(m2, __shfl_xor(m2, off, 64));
            float e = __expf(sc - m2);
            float se = e;
            #pragma unroll
            for (int off = 1; off < 64; off <<= 1) se += __shfl_xor(se, off, 64);
            float wgt = e / se;
            const int bb = row >> 12, n = row & 4095;
            float qx = p1[(size_t)bb*3*N_ + n];
            float qy = p1[(size_t)bb*3*N_ + N_ + n];
            float qz = p1[(size_t)bb*3*N_ + 2*N_ + n];
            float4 f4 = feats4[row*64 + l];
            float ox = wgt * (f4.x + qx), oy = wgt * (f4.y + qy), oz = wgt * (f4.z + qz);
            #pragma unroll
            for (int off = 1; off < 64; off <<= 1) {
                ox += __shfl_xor(ox, off, 64);
                oy += __shfl_xor(oy, off, 64);
                oz += __shfl_xor(oz, off, 64);
            }
            if (l == 0) {
                outp[bb*3*N_ + 0*N_ + n] = ox;
                outp[bb*3*N_ + 1*N_ + n] = oy;
                outp[bb*3*N_ + 2*N_ + n] = oz;
            }
        }
    }
}

// ---------------------------------------------------------------------------
extern "C" void kernel_launch(void* const* d_in, const int* in_sizes, int n_in,
                              void* d_out, int out_size, void* d_ws, size_t ws_size,
                              hipStream_t stream)
{
    const float* p1  = (const float*)d_in[0];
    const float* p2  = (const float*)d_in[1];
    // d_in[2] = k (always 32), d_in[3] = t (unused by reference)
    const float* W1  = (const float*)d_in[4];
    const float* g1  = (const float*)d_in[6];
    const float* be1 = (const float*)d_in[7];
    const float* W2  = (const float*)d_in[8];
    const float* g2  = (const float*)d_in[10];
    const float* be2 = (const float*)d_in[11];
    const float* W3  = (const float*)d_in[12];
    const float* g3  = (const float*)d_in[14];
    const float* be3 = (const float*)d_in[15];
    // b1 cancels through bn1 (moment fold); b2/b3 cancel through bn2/bn3.

    char* ws = (char*)d_ws;
    const size_t OFF_FEATS = 4096;
    const size_t OFF_Y2    = OFF_FEATS + (size_t)MTOT * 4 * 4;          // 16 MB feats
    const size_t NEEDED    = OFF_Y2 + (size_t)MTOT * 64 * 2;            // 128 MB y2/x3
    if (ws_size < NEEDED) return;  // fail visibly (wrong output) rather than fault

    float* s2S = (float*)(ws + 512);  float* s2Q = (float*)(ws + 768);
    float* s3S = (float*)(ws + 1024); float* s3Q = (float*)(ws + 1536);
    float* mom = (float*)(ws + 2048);            // 14 counters, 64-B stride each
    float* feats = (float*)(ws + OFF_FEATS);
    ushort* y2F  = (ushort*)(ws + OFF_Y2);       // y2 frags, overwritten with x3

    hipMemsetAsync(ws, 0, 4096, stream);  // zero stats + padded moment counters

    knn_kernel<<<768, 256, 0, stream>>>(p1, p2, feats, mom);
    conv2_mfma<<<1024, 256, 0, stream>>>(feats, W1, g1, be1, W2, mom,
                                         y2F, s2S, s2Q);
    conv3_stats<<<1024, 256, 0, stream>>>(y2F, g2, be2, W3,
                                          s2S, s2Q, s3S, s3Q);
    conv3_final<<<1024, 256, 0, stream>>>(y2F, W3, g3, be3, s3S, s3Q,
                                          (const float4*)feats, p1,
                                          (float*)d_out);
}